// Round 2
// baseline (292.606 us; speedup 1.0000x reference)
//
#include <hip/hip_runtime.h>

// Problem: B=32, T=2048, D=128, H=256. fp32 inputs/outputs (per reference).
//
// Pipeline:
//  1) GEMM1 (x @ W1^T + b1), fp32, two H-halves of 128 cols -> A f32
//  2) LIF scan over T (speculative chunks: CH=256, warm-up W=128 from v=0;
//     contraction + hard-reset resync => exact vs sequential scan) -> spikes bf16
//  3) GEMM2 (spikes(bf16) @ W2^T + b2) -> A f32
//  4) LIF scan 2 -> S2 bf16
//  5) residual + LayerNorm over D=128, fp32 out
//
// Workspace (80 MB):
//   A  f32  [65536][128] : ws[0        .. 33554432)   (GEMM1 halves, then GEMM2 out)
//   S1 bf16 [65536][256] : ws[33554432 .. 67108864)
//   S2 bf16 [65536][128] : ws[67108864 .. 83886080)

__device__ __forceinline__ float bf_lo(unsigned u) { return __uint_as_float(u << 16); }
__device__ __forceinline__ float bf_hi(unsigned u) { return __uint_as_float(u & 0xFFFF0000u); }

// C[m][n] = sum_k A[m][k]*Bw[n][k] + bias[n].  A fp32 or bf16 (ABF), Bw/bias fp32,
// C fp32 [M x ldc]. Tile 64x64, 256 threads, 4x4 per thread (n strided by 16),
// K multiple of 32.
template <int K, bool ABF>
__global__ __launch_bounds__(256) void gemm_bias_kernel(
    const void* __restrict__ Av,
    const float* __restrict__ Bw,
    const float* __restrict__ bias,
    float* __restrict__ C, int ldc)
{
    __shared__ float As[64][36];   // stride 36 = 4 mod 32: b128 reads 2-way max
    __shared__ float Bs[64][36];
    const int mBase = blockIdx.x * 64;
    const int nBase = blockIdx.y * 64;
    const int tid = threadIdx.x;
    const int tx = tid & 15;        // n-lane 0..15
    const int ty = tid >> 4;        // m-group 0..15
    const int lr = tid >> 2;        // load row 0..63
    const int lc = (tid & 3) * 8;   // load col 0,8,16,24

    float acc[4][4];
#pragma unroll
    for (int i = 0; i < 4; ++i)
#pragma unroll
        for (int j = 0; j < 4; ++j) acc[i][j] = 0.0f;

    const float* apf = (const float*)Av + (size_t)(mBase + lr) * K + lc;
    const unsigned short* aph = (const unsigned short*)Av + (size_t)(mBase + lr) * K + lc;
    const float* bp = Bw + (size_t)(nBase + lr) * K + lc;

    for (int k0 = 0; k0 < K; k0 += 32) {
        float a[8];
        if (ABF) {
            uint4 ua = *(const uint4*)(aph + k0);
            a[0] = bf_lo(ua.x); a[1] = bf_hi(ua.x);
            a[2] = bf_lo(ua.y); a[3] = bf_hi(ua.y);
            a[4] = bf_lo(ua.z); a[5] = bf_hi(ua.z);
            a[6] = bf_lo(ua.w); a[7] = bf_hi(ua.w);
        } else {
            float4 f0 = *(const float4*)(apf + k0);
            float4 f1 = *(const float4*)(apf + k0 + 4);
            a[0] = f0.x; a[1] = f0.y; a[2] = f0.z; a[3] = f0.w;
            a[4] = f1.x; a[5] = f1.y; a[6] = f1.z; a[7] = f1.w;
        }
        float4 w0 = *(const float4*)(bp + k0);
        float4 w1 = *(const float4*)(bp + k0 + 4);

        __syncthreads();
        {
            float* aw = &As[lr][lc];
#pragma unroll
            for (int q = 0; q < 8; ++q) aw[q] = a[q];
            float* bw = &Bs[lr][lc];
            bw[0] = w0.x; bw[1] = w0.y; bw[2] = w0.z; bw[3] = w0.w;
            bw[4] = w1.x; bw[5] = w1.y; bw[6] = w1.z; bw[7] = w1.w;
        }
        __syncthreads();

#pragma unroll
        for (int kk = 0; kk < 32; kk += 4) {
            float4 av[4], bv[4];
#pragma unroll
            for (int i = 0; i < 4; ++i) av[i] = *(const float4*)&As[ty * 4 + i][kk];
#pragma unroll
            for (int j = 0; j < 4; ++j) bv[j] = *(const float4*)&Bs[tx + 16 * j][kk];
#pragma unroll
            for (int i = 0; i < 4; ++i)
#pragma unroll
                for (int j = 0; j < 4; ++j) {
                    acc[i][j] = fmaf(av[i].x, bv[j].x, acc[i][j]);
                    acc[i][j] = fmaf(av[i].y, bv[j].y, acc[i][j]);
                    acc[i][j] = fmaf(av[i].z, bv[j].z, acc[i][j]);
                    acc[i][j] = fmaf(av[i].w, bv[j].w, acc[i][j]);
                }
        }
    }

    float bfv[4];
#pragma unroll
    for (int j = 0; j < 4; ++j) bfv[j] = bias[nBase + tx + 16 * j];
#pragma unroll
    for (int i = 0; i < 4; ++i) {
        float* crow = &C[(size_t)(mBase + ty * 4 + i) * ldc + nBase];
#pragma unroll
        for (int j = 0; j < 4; ++j) crow[tx + 16 * j] = acc[i][j] + bfv[j];
    }
}

// Speculative chunked LIF scan. blockDim.x == Cin (=128). grid: (T/CH, B).
// Input A: [B*T][Cin] fp32. Output S: [B*T][Cout] bf16 spikes at column offset.
__global__ __launch_bounds__(128) void lif_scan_kernel(
    const float* __restrict__ A, unsigned short* __restrict__ S,
    int T, int Cin, int Cout, int coutOff, int CH, int W)
{
    const int b = blockIdx.y;
    const int chunk = blockIdx.x;
    const int c = threadIdx.x;
    const int t0 = chunk * CH;
    int ts = t0 - W; if (ts < 0) ts = 0;

    const float* __restrict__ base = A + (size_t)b * T * Cin + c;
    unsigned short* __restrict__ sb = S + (size_t)b * T * Cout + coutOff + c;

    float v = 0.0f;
    // warm-up (speculative; contraction + reset-resync converge to exact state)
    for (int t = ts; t < t0; t += 8) {
        float a[8];
#pragma unroll
        for (int k = 0; k < 8; ++k) a[k] = base[(size_t)(t + k) * Cin];
#pragma unroll
        for (int k = 0; k < 8; ++k) {
            float h = v + (a[k] - v) * 0.5f;   // exact reference formula
            v = (h >= 1.0f) ? 0.0f : h;
        }
    }
    // main
    for (int t = t0; t < t0 + CH; t += 8) {
        float a[8];
#pragma unroll
        for (int k = 0; k < 8; ++k) a[k] = base[(size_t)(t + k) * Cin];
#pragma unroll
        for (int k = 0; k < 8; ++k) {
            float h = v + (a[k] - v) * 0.5f;
            bool sp = (h >= 1.0f);
            v = sp ? 0.0f : h;
            sb[(size_t)(t + k) * Cout] = sp ? (unsigned short)0x3F80 : (unsigned short)0;
        }
    }
}

// y = x + s2; LayerNorm over D=128; fp32 in/out, s2 bf16. One wave per row.
__global__ __launch_bounds__(256) void resid_ln_kernel(
    const float* __restrict__ x,
    const unsigned short* __restrict__ s2,
    const float* __restrict__ lnw,
    const float* __restrict__ lnb,
    float* __restrict__ out)
{
    const int row = blockIdx.x * 4 + (threadIdx.x >> 6);
    const int lane = threadIdx.x & 63;
    const size_t base = (size_t)row * 128 + lane * 2;

    float2 xv = *(const float2*)(x + base);
    unsigned us = *(const unsigned*)(s2 + base);
    float y0 = xv.x + bf_lo(us);
    float y1 = xv.y + bf_hi(us);

    float sum = y0 + y1;
    float ss = y0 * y0 + y1 * y1;
#pragma unroll
    for (int off = 32; off > 0; off >>= 1) {
        sum += __shfl_xor(sum, off, 64);
        ss  += __shfl_xor(ss, off, 64);
    }
    float mu = sum * (1.0f / 128.0f);
    float var = ss * (1.0f / 128.0f) - mu * mu;
    float inv = rsqrtf(var + 1e-5f);

    float2 wv = *(const float2*)(lnw + lane * 2);
    float2 bv = *(const float2*)(lnb + lane * 2);
    float2 o;
    o.x = (y0 - mu) * inv * wv.x + bv.x;
    o.y = (y1 - mu) * inv * wv.y + bv.y;
    *(float2*)(out + base) = o;
}

extern "C" void kernel_launch(void* const* d_in, const int* in_sizes, int n_in,
                              void* d_out, int out_size, void* d_ws, size_t ws_size,
                              hipStream_t stream)
{
    const float* x   = (const float*)d_in[0];
    const float* W1  = (const float*)d_in[1];
    const float* b1  = (const float*)d_in[2];
    const float* W2  = (const float*)d_in[3];
    const float* b2  = (const float*)d_in[4];
    const float* lnw = (const float*)d_in[5];
    const float* lnb = (const float*)d_in[6];
    float* out = (float*)d_out;

    char* ws = (char*)d_ws;
    float* A = (float*)ws;                                  // [65536][128] f32
    unsigned short* S1 = (unsigned short*)(ws + 33554432);  // [65536][256] bf16
    unsigned short* S2 = (unsigned short*)(ws + 67108864);  // [65536][128] bf16

    const int M = 32 * 2048;   // 65536 rows (b-major, t within)
    const int T = 2048;

    dim3 gGemm(M / 64, 2);     // 64x64 tiles
    dim3 gScan(T / 256, 32);   // chunks x B
    dim3 gLN(M / 4);

    // GEMM1 half 0: h in [0,128)
    gemm_bias_kernel<128, false><<<gGemm, 256, 0, stream>>>(x, W1, b1, A, 128);
    lif_scan_kernel<<<gScan, 128, 0, stream>>>(A, S1, T, 128, 256, 0, 256, 128);
    // GEMM1 half 1: h in [128,256)
    gemm_bias_kernel<128, false><<<gGemm, 256, 0, stream>>>(x, W1 + 128 * 128, b1 + 128, A, 128);
    lif_scan_kernel<<<gScan, 128, 0, stream>>>(A, S1, T, 128, 256, 128, 256, 128);
    // GEMM2: spikes [M x 256] bf16 @ W2^T -> [M x 128]
    gemm_bias_kernel<256, true><<<gGemm, 256, 0, stream>>>(S1, W2, b2, A, 128);
    lif_scan_kernel<<<gScan, 128, 0, stream>>>(A, S2, T, 128, 128, 0, 256, 128);
    // residual + LayerNorm
    resid_ln_kernel<<<gLN, 256, 0, stream>>>(x, S2, lnw, lnb, out);
}

// Round 3
// 197.339 us; speedup vs baseline: 1.4828x; 1.4828x over previous
//
#include <hip/hip_runtime.h>

// B=32, T=2048, D=128, H=256. fp32 in/out.
// GEMMs via MFMA bf16 with exact 3-plane splitting (err ~2^-27, below fp32
// accumulation noise, so spike decisions match the R2 fp32 kernel's class).
//   GEMM1: A=x (3-split in-kernel), B=W1 (3-split precomputed)  -> 6 passes
//   GEMM2: A=spikes (exact bf16),   B=W2 (3-split precomputed)  -> 3 passes
// Scans: speculative chunks (CH=256, W=128), unchanged from R2 (passed).
//
// ws layout (halves path, 67.5 MB):
//   A  f32  [65536][128] @ 0        (h1 halves, then h2)
//   S1 bf16 [65536][256] @ 32 MB    (S2 reuses this region after GEMM2)
//   Wsplits 6*64 KB      @ 64 MB
// full path (ws >= 96.4+ MB): A f32 [65536][256] @0; S1 @64MB; Wsplits @96MB.

typedef __attribute__((ext_vector_type(8))) short short8;
typedef __attribute__((ext_vector_type(4))) float f32x4;

#define MFMA16(a, b, c) __builtin_amdgcn_mfma_f32_16x16x32_bf16(a, b, c, 0, 0, 0)

__device__ __forceinline__ unsigned short f2bf(float f) {
    unsigned u = __float_as_uint(f);
    u += 0x7FFFu + ((u >> 16) & 1u);   // RNE
    return (unsigned short)(u >> 16);
}
__device__ __forceinline__ float bf2f(unsigned short s) { return __uint_as_float(((unsigned)s) << 16); }

// Split W1 (32768) and W2 (32768) into 3 bf16 planes each.
// out: [W1a, W1b, W1c, W2a, W2b, W2c], each 32768 shorts.
__global__ __launch_bounds__(256) void wsplit_kernel(
    const float* __restrict__ W1, const float* __restrict__ W2,
    unsigned short* __restrict__ out)
{
    int i = blockIdx.x * 256 + threadIdx.x;          // 0..65535
    const float* src = (i < 32768) ? W1 : W2;
    unsigned short* dst = out + ((i < 32768) ? 0 : 3 * 32768);
    int j = i & 32767;
    float v = src[j];
    unsigned short a = f2bf(v); float r = v - bf2f(a);
    unsigned short b = f2bf(r); r = r - bf2f(b);
    unsigned short c = f2bf(r);
    dst[j] = a; dst[32768 + j] = b; dst[2 * 32768 + j] = c;
}

__device__ __forceinline__ void store16(unsigned short* dst, const unsigned short* s) {
    uint4 u0, u1;
    u0.x = s[0]  | ((unsigned)s[1]  << 16); u0.y = s[2]  | ((unsigned)s[3]  << 16);
    u0.z = s[4]  | ((unsigned)s[5]  << 16); u0.w = s[6]  | ((unsigned)s[7]  << 16);
    u1.x = s[8]  | ((unsigned)s[9]  << 16); u1.y = s[10] | ((unsigned)s[11] << 16);
    u1.z = s[12] | ((unsigned)s[13] << 16); u1.w = s[14] | ((unsigned)s[15] << 16);
    *(uint4*)dst = u0; *(uint4*)(dst + 8) = u1;
}

// C[m][n] = sum_k A[m][k]*W[n][k] + bias[n], C fp32 [grid.x*128 x ldc].
// MODE 0: A fp32, split in-kernel to 3 planes; 6 MFMA passes.
// MODE 1: A bf16 (spikes, exact);             3 MFMA passes.
// B1/B2/B3: bf16 planes [N][K] row-major. Block tile 128x128, 4 waves.
template <int K, int MODE>
__global__ __launch_bounds__(256, 2) void mfma_gemm_kernel(
    const void* __restrict__ Av,
    const unsigned short* __restrict__ B1,
    const unsigned short* __restrict__ B2,
    const unsigned short* __restrict__ B3,
    const float* __restrict__ bias,
    float* __restrict__ C, int ldc)
{
    constexpr int LDSX = 40;                    // short stride: 80B rows, pad
    constexpr int NA = (MODE == 0) ? 3 : 1;
    __shared__ unsigned short As[NA][128 * LDSX];
    __shared__ unsigned short Bs[3][128 * LDSX];

    const int tid = threadIdx.x;
    const int lane = tid & 63;
    const int wave = tid >> 6;
    const int waveM = (wave >> 1) * 64;
    const int waveN = (wave & 1) * 64;
    const int mBase = blockIdx.x * 128;
    const int nBase = blockIdx.y * 128;

    const int lr = tid >> 1;                    // staging row 0..127
    const int lh = (tid & 1) * 16;              // k offset 0/16

    f32x4 acc[4][4];
#pragma unroll
    for (int i = 0; i < 4; ++i)
#pragma unroll
        for (int j = 0; j < 4; ++j) acc[i][j] = (f32x4){0.f, 0.f, 0.f, 0.f};

    const float* af = (const float*)Av + (size_t)(mBase + lr) * K + lh;
    const unsigned short* ab = (const unsigned short*)Av + (size_t)(mBase + lr) * K + lh;
    const size_t boff = (size_t)(nBase + lr) * K + lh;

    const int fr = lane & 15;                   // frag row (m or n)
    const int fo = (lane >> 4) * 8;             // frag k offset

    for (int k0 = 0; k0 < K; k0 += 32) {
        // ---- global loads ----
        uint4 w1a = *(const uint4*)(B1 + boff + k0), w1b = *(const uint4*)(B1 + boff + k0 + 8);
        uint4 w2a = *(const uint4*)(B2 + boff + k0), w2b = *(const uint4*)(B2 + boff + k0 + 8);
        uint4 w3a = *(const uint4*)(B3 + boff + k0), w3b = *(const uint4*)(B3 + boff + k0 + 8);

        unsigned short as1[16], as2[16], as3[16];
        uint4 sa0, sa1;
        if constexpr (MODE == 0) {
            float4 fv[4];
#pragma unroll
            for (int q = 0; q < 4; ++q) fv[q] = *(const float4*)(af + k0 + q * 4);
            const float* fs = (const float*)fv;
#pragma unroll
            for (int q = 0; q < 16; ++q) {
                float v = fs[q];
                as1[q] = f2bf(v); float r = v - bf2f(as1[q]);
                as2[q] = f2bf(r); r = r - bf2f(as2[q]);
                as3[q] = f2bf(r);
            }
        } else {
            sa0 = *(const uint4*)(ab + k0);
            sa1 = *(const uint4*)(ab + k0 + 8);
        }

        __syncthreads();
        // ---- LDS stores ----
        {
            unsigned short* bw0 = &Bs[0][lr * LDSX + lh];
            *(uint4*)bw0 = w1a; *(uint4*)(bw0 + 8) = w1b;
            unsigned short* bw1 = &Bs[1][lr * LDSX + lh];
            *(uint4*)bw1 = w2a; *(uint4*)(bw1 + 8) = w2b;
            unsigned short* bw2 = &Bs[2][lr * LDSX + lh];
            *(uint4*)bw2 = w3a; *(uint4*)(bw2 + 8) = w3b;
            if constexpr (MODE == 0) {
                store16(&As[0][lr * LDSX + lh], as1);
                store16(&As[1][lr * LDSX + lh], as2);
                store16(&As[2][lr * LDSX + lh], as3);
            } else {
                unsigned short* aw = &As[0][lr * LDSX + lh];
                *(uint4*)aw = sa0; *(uint4*)(aw + 8) = sa1;
            }
        }
        __syncthreads();

        // ---- MFMA ----
        short8 a1[4], a2[4], a3[4];
#pragma unroll
        for (int i = 0; i < 4; ++i) {
            int ro = (waveM + i * 16 + fr) * LDSX + fo;
            a1[i] = *(const short8*)&As[0][ro];
            if constexpr (MODE == 0) {
                a2[i] = *(const short8*)&As[1][ro];
                a3[i] = *(const short8*)&As[2][ro];
            }
        }
#pragma unroll
        for (int j = 0; j < 4; ++j) {
            int ro = (waveN + j * 16 + fr) * LDSX + fo;
            short8 b1v = *(const short8*)&Bs[0][ro];
            short8 b2v = *(const short8*)&Bs[1][ro];
            short8 b3v = *(const short8*)&Bs[2][ro];
#pragma unroll
            for (int i = 0; i < 4; ++i) {
                if constexpr (MODE == 0) {
                    acc[i][j] = MFMA16(a1[i], b1v, acc[i][j]);
                    acc[i][j] = MFMA16(a1[i], b2v, acc[i][j]);
                    acc[i][j] = MFMA16(a2[i], b1v, acc[i][j]);
                    acc[i][j] = MFMA16(a1[i], b3v, acc[i][j]);
                    acc[i][j] = MFMA16(a3[i], b1v, acc[i][j]);
                    acc[i][j] = MFMA16(a2[i], b2v, acc[i][j]);
                } else {
                    acc[i][j] = MFMA16(a1[i], b1v, acc[i][j]);
                    acc[i][j] = MFMA16(a1[i], b2v, acc[i][j]);
                    acc[i][j] = MFMA16(a1[i], b3v, acc[i][j]);
                }
            }
        }
    }

    // ---- epilogue: C[m][n] = acc + bias[n] ----
    const int qr = (lane >> 4) * 4;             // C/D: col=lane&15, row=quad*4+reg
#pragma unroll
    for (int j = 0; j < 4; ++j) {
        float bv = bias[nBase + waveN + j * 16 + fr];
#pragma unroll
        for (int i = 0; i < 4; ++i) {
            float* cp = C + (size_t)(mBase + waveM + i * 16 + qr) * ldc
                          + (nBase + waveN + j * 16 + fr);
#pragma unroll
            for (int r = 0; r < 4; ++r)
                cp[(size_t)r * ldc] = acc[i][j][r] + bv;
        }
    }
}

// Speculative chunked LIF scan. blockDim.x == Cin. grid: (T/CH, B).
__global__ __launch_bounds__(256) void lif_scan_kernel(
    const float* __restrict__ A, unsigned short* __restrict__ S,
    int T, int Cin, int Cout, int coutOff, int CH, int W)
{
    const int b = blockIdx.y;
    const int c = threadIdx.x;
    const int t0 = blockIdx.x * CH;
    int ts = t0 - W; if (ts < 0) ts = 0;

    const float* __restrict__ base = A + (size_t)b * T * Cin + c;
    unsigned short* __restrict__ sb = S + (size_t)b * T * Cout + coutOff + c;

    float v = 0.0f;
    for (int t = ts; t < t0; t += 8) {
        float a[8];
#pragma unroll
        for (int k = 0; k < 8; ++k) a[k] = base[(size_t)(t + k) * Cin];
#pragma unroll
        for (int k = 0; k < 8; ++k) {
            float h = v + (a[k] - v) * 0.5f;
            v = (h >= 1.0f) ? 0.0f : h;
        }
    }
    for (int t = t0; t < t0 + CH; t += 8) {
        float a[8];
#pragma unroll
        for (int k = 0; k < 8; ++k) a[k] = base[(size_t)(t + k) * Cin];
#pragma unroll
        for (int k = 0; k < 8; ++k) {
            float h = v + (a[k] - v) * 0.5f;
            bool sp = (h >= 1.0f);
            v = sp ? 0.0f : h;
            sb[(size_t)(t + k) * Cout] = sp ? (unsigned short)0x3F80 : (unsigned short)0;
        }
    }
}

// y = x + s2; LayerNorm over D=128; fp32 out. One wave per row.
__global__ __launch_bounds__(256) void resid_ln_kernel(
    const float* __restrict__ x,
    const unsigned short* __restrict__ s2,
    const float* __restrict__ lnw,
    const float* __restrict__ lnb,
    float* __restrict__ out)
{
    const int row = blockIdx.x * 4 + (threadIdx.x >> 6);
    const int lane = threadIdx.x & 63;
    const size_t base = (size_t)row * 128 + lane * 2;

    float2 xv = *(const float2*)(x + base);
    unsigned us = *(const unsigned*)(s2 + base);
    float y0 = xv.x + bf2f((unsigned short)(us & 0xFFFF));
    float y1 = xv.y + bf2f((unsigned short)(us >> 16));

    float sum = y0 + y1;
    float ss = y0 * y0 + y1 * y1;
#pragma unroll
    for (int off = 32; off > 0; off >>= 1) {
        sum += __shfl_xor(sum, off, 64);
        ss  += __shfl_xor(ss, off, 64);
    }
    float mu = sum * (1.0f / 128.0f);
    float var = ss * (1.0f / 128.0f) - mu * mu;
    float inv = rsqrtf(var + 1e-5f);

    float2 wv = *(const float2*)(lnw + lane * 2);
    float2 bv = *(const float2*)(lnb + lane * 2);
    float2 o;
    o.x = (y0 - mu) * inv * wv.x + bv.x;
    o.y = (y1 - mu) * inv * wv.y + bv.y;
    *(float2*)(out + base) = o;
}

extern "C" void kernel_launch(void* const* d_in, const int* in_sizes, int n_in,
                              void* d_out, int out_size, void* d_ws, size_t ws_size,
                              hipStream_t stream)
{
    const float* x   = (const float*)d_in[0];
    const float* W1  = (const float*)d_in[1];
    const float* b1  = (const float*)d_in[2];
    const float* W2  = (const float*)d_in[3];
    const float* b2  = (const float*)d_in[4];
    const float* lnw = (const float*)d_in[5];
    const float* lnb = (const float*)d_in[6];
    float* out = (float*)d_out;

    const int M = 65536, T = 2048;
    char* ws = (char*)d_ws;
    const bool big = ws_size >= (size_t)101056512;  // full-N path fits

    dim3 gG(M / 128, 1);
    dim3 gScan(T / 256, 32);
    dim3 gLN(M / 4);

    if (big) {
        float* A = (float*)ws;                                   // [M][256] then [M][128]
        unsigned short* S1 = (unsigned short*)(ws + 67108864);   // [M][256]
        unsigned short* S2 = S1;                                 // reused after GEMM2
        unsigned short* Wsp = (unsigned short*)(ws + 100663296); // 6 planes x 32768

        wsplit_kernel<<<256, 256, 0, stream>>>(W1, W2, Wsp);
        dim3 gG1(M / 128, 2);
        mfma_gemm_kernel<128, 0><<<gG1, 256, 0, stream>>>(
            x, Wsp, Wsp + 32768, Wsp + 65536, b1, A, 256);
        lif_scan_kernel<<<gScan, 256, 0, stream>>>(A, S1, T, 256, 256, 0, 256, 128);
        mfma_gemm_kernel<256, 1><<<gG, 256, 0, stream>>>(
            S1, Wsp + 98304, Wsp + 131072, Wsp + 163840, b2, A, 128);
        lif_scan_kernel<<<gScan, 128, 0, stream>>>(A, (unsigned short*)S2, T, 128, 128, 0, 256, 128);
        resid_ln_kernel<<<gLN, 256, 0, stream>>>(x, S2, lnw, lnb, out);
    } else {
        float* A = (float*)ws;                                   // [M][128]
        unsigned short* S1 = (unsigned short*)(ws + 33554432);   // [M][256]
        unsigned short* S2 = S1;                                 // reused after GEMM2
        unsigned short* Wsp = (unsigned short*)(ws + 67108864);  // 6 planes x 32768

        wsplit_kernel<<<256, 256, 0, stream>>>(W1, W2, Wsp);
        // GEMM1 half 0 (H cols 0..127)
        mfma_gemm_kernel<128, 0><<<gG, 256, 0, stream>>>(
            x, Wsp, Wsp + 32768, Wsp + 65536, b1, A, 128);
        lif_scan_kernel<<<gScan, 128, 0, stream>>>(A, S1, T, 128, 256, 0, 256, 128);
        // GEMM1 half 1 (H cols 128..255): W1 plane row offset 128*128
        mfma_gemm_kernel<128, 0><<<gG, 256, 0, stream>>>(
            x, Wsp + 16384, Wsp + 32768 + 16384, Wsp + 65536 + 16384, b1 + 128, A, 128);
        lif_scan_kernel<<<gScan, 128, 0, stream>>>(A, S1, T, 128, 256, 128, 256, 128);
        // GEMM2
        mfma_gemm_kernel<256, 1><<<gG, 256, 0, stream>>>(
            S1, Wsp + 98304, Wsp + 131072, Wsp + 163840, b2, A, 128);
        lif_scan_kernel<<<gScan, 128, 0, stream>>>(A, S2, T, 128, 128, 0, 256, 128);
        resid_ln_kernel<<<gLN, 256, 0, stream>>>(x, S2, lnw, lnb, out);
    }
}

// Round 4
// 177.348 us; speedup vs baseline: 1.6499x; 1.1127x over previous
//
#include <hip/hip_runtime.h>

// B=32, T=2048, D=128, H=256. fp32 in/out.
// GEMMs via MFMA fp16 with exact 2-plane splitting: x = a + b, a=fp16(x),
// b=fp16(x-a) reconstructs x to 2^-24 relative (fp32 class).
//   GEMM1: A=x (2-split in-kernel), B=W1 (2-split) -> 3 passes (aa, ab, ba)
//   GEMM2: A=spikes (exact fp16),   B=W2 (2-split) -> 2 passes
// Scans: speculative chunks (CH=256, W=128) — verified exact in R2/R3.
// scan2 fused with residual+LayerNorm (y-rows buffered in LDS).
//
// ws layout (96.25 MB):
//   A   f32  [65536][256] @ 0      (h1; then GEMM2 writes h2 [65536][128] here)
//   S1  fp16 [65536][256] @ 64 MB
//   Wp  fp16 4 planes x 32768 @ 96 MB  [W1a, W1b, W2a, W2b]

typedef _Float16 half8 __attribute__((ext_vector_type(8)));
typedef float f32x4 __attribute__((ext_vector_type(4)));

#define MFMA_F16(a, b, c) __builtin_amdgcn_mfma_f32_16x16x32_f16(a, b, c, 0, 0, 0)

__device__ __forceinline__ unsigned short h2u(_Float16 h) {
    union { _Float16 h; unsigned short u; } x; x.h = h; return x.u;
}

__device__ __forceinline__ void store16(unsigned short* dst, const unsigned short* s) {
    uint4 u0, u1;
    u0.x = s[0]  | ((unsigned)s[1]  << 16); u0.y = s[2]  | ((unsigned)s[3]  << 16);
    u0.z = s[4]  | ((unsigned)s[5]  << 16); u0.w = s[6]  | ((unsigned)s[7]  << 16);
    u1.x = s[8]  | ((unsigned)s[9]  << 16); u1.y = s[10] | ((unsigned)s[11] << 16);
    u1.z = s[12] | ((unsigned)s[13] << 16); u1.w = s[14] | ((unsigned)s[15] << 16);
    *(uint4*)dst = u0; *(uint4*)(dst + 8) = u1;
}

// Split W1 (32768) and W2 (32768) into 2 fp16 planes each.
__global__ __launch_bounds__(256) void wsplit_kernel(
    const float* __restrict__ W1, const float* __restrict__ W2,
    unsigned short* __restrict__ out)
{
    int i = blockIdx.x * 256 + threadIdx.x;          // 0..65535
    const float* src = (i < 32768) ? W1 : W2;
    unsigned short* dst = out + ((i < 32768) ? 0 : 2 * 32768);
    int j = i & 32767;
    float v = src[j];
    _Float16 a = (_Float16)v;
    float r = v - (float)a;
    _Float16 b = (_Float16)r;
    dst[j] = h2u(a); dst[32768 + j] = h2u(b);
}

// GEMM1: C[m][n] = sum_k X[m][k]*W1[n][k] + b1[n].  X fp32 (split in-kernel),
// W planes fp16. Block 128x128, 4 waves, 3 MFMA passes. K=128. C fp32 ldc=256.
__global__ __launch_bounds__(256, 3) void gemm1_kernel(
    const float* __restrict__ X,
    const unsigned short* __restrict__ B1,
    const unsigned short* __restrict__ B2,
    const float* __restrict__ bias,
    float* __restrict__ C)
{
    constexpr int K = 128, LDSX = 40;   // 40-short rows: 20-word stride -> 2-way max
    __shared__ unsigned short As[2][128 * LDSX];
    __shared__ unsigned short Bs[2][128 * LDSX];

    const int tid = threadIdx.x;
    const int lane = tid & 63;
    const int wave = tid >> 6;
    const int waveM = (wave >> 1) * 64;
    const int waveN = (wave & 1) * 64;
    const int mBase = blockIdx.x * 128;
    const int nBase = blockIdx.y * 128;
    const int lr = tid >> 1;            // staging row 0..127
    const int lh = (tid & 1) * 16;      // k offset 0/16

    f32x4 acc[4][4];
#pragma unroll
    for (int i = 0; i < 4; ++i)
#pragma unroll
        for (int j = 0; j < 4; ++j) acc[i][j] = (f32x4){0.f, 0.f, 0.f, 0.f};

    const float* xp = X + (size_t)(mBase + lr) * K + lh;
    const unsigned short* bp1 = B1 + (size_t)(nBase + lr) * K + lh;
    const unsigned short* bp2 = B2 + (size_t)(nBase + lr) * K + lh;

    const int fr = lane & 15;
    const int fo = (lane >> 4) * 8;

#pragma unroll
    for (int k0 = 0; k0 < K; k0 += 32) {
        float4 f0 = *(const float4*)(xp + k0);
        float4 f1 = *(const float4*)(xp + k0 + 4);
        float4 f2 = *(const float4*)(xp + k0 + 8);
        float4 f3 = *(const float4*)(xp + k0 + 12);
        uint4 w1a = *(const uint4*)(bp1 + k0), w1b = *(const uint4*)(bp1 + k0 + 8);
        uint4 w2a = *(const uint4*)(bp2 + k0), w2b = *(const uint4*)(bp2 + k0 + 8);

        unsigned short sa[16], sb[16];
        {
            float fs[16] = {f0.x, f0.y, f0.z, f0.w, f1.x, f1.y, f1.z, f1.w,
                            f2.x, f2.y, f2.z, f2.w, f3.x, f3.y, f3.z, f3.w};
#pragma unroll
            for (int q = 0; q < 16; ++q) {
                _Float16 a = (_Float16)fs[q];
                float r = fs[q] - (float)a;
                _Float16 b = (_Float16)r;
                sa[q] = h2u(a); sb[q] = h2u(b);
            }
        }

        __syncthreads();
        store16(&As[0][lr * LDSX + lh], sa);
        store16(&As[1][lr * LDSX + lh], sb);
        {
            unsigned short* bw0 = &Bs[0][lr * LDSX + lh];
            *(uint4*)bw0 = w1a; *(uint4*)(bw0 + 8) = w1b;
            unsigned short* bw1 = &Bs[1][lr * LDSX + lh];
            *(uint4*)bw1 = w2a; *(uint4*)(bw1 + 8) = w2b;
        }
        __syncthreads();

        half8 a1[4], a2[4];
#pragma unroll
        for (int i = 0; i < 4; ++i) {
            int ro = (waveM + i * 16 + fr) * LDSX + fo;
            a1[i] = *(const half8*)&As[0][ro];
            a2[i] = *(const half8*)&As[1][ro];
        }
#pragma unroll
        for (int j = 0; j < 4; ++j) {
            int ro = (waveN + j * 16 + fr) * LDSX + fo;
            half8 b1v = *(const half8*)&Bs[0][ro];
            half8 b2v = *(const half8*)&Bs[1][ro];
#pragma unroll
            for (int i = 0; i < 4; ++i) {
                acc[i][j] = MFMA_F16(a1[i], b1v, acc[i][j]);   // aa
                acc[i][j] = MFMA_F16(a1[i], b2v, acc[i][j]);   // ab
                acc[i][j] = MFMA_F16(a2[i], b1v, acc[i][j]);   // ba
            }
        }
    }

    const int qr = (lane >> 4) * 4;   // C/D: col=lane&15, row=quad*4+reg
#pragma unroll
    for (int j = 0; j < 4; ++j) {
        float bv = bias[nBase + waveN + j * 16 + fr];
#pragma unroll
        for (int i = 0; i < 4; ++i) {
            float* cp = C + (size_t)(mBase + waveM + i * 16 + qr) * 256
                          + (nBase + waveN + j * 16 + fr);
#pragma unroll
            for (int r = 0; r < 4; ++r)
                cp[(size_t)r * 256] = acc[i][j][r] + bv;
        }
    }
}

// GEMM2: C[m][n] = sum_k S1[m][k]*W2[n][k] + b2[n]. S1 fp16 exact spikes,
// W planes fp16, 2 passes. K=256, N=128. C fp32 ldc=128.
__global__ __launch_bounds__(256, 3) void gemm2_kernel(
    const unsigned short* __restrict__ S1,
    const unsigned short* __restrict__ B1,
    const unsigned short* __restrict__ B2,
    const float* __restrict__ bias,
    float* __restrict__ C)
{
    constexpr int K = 256, LDSX = 40;
    __shared__ unsigned short As[128 * LDSX];
    __shared__ unsigned short Bs[2][128 * LDSX];

    const int tid = threadIdx.x;
    const int lane = tid & 63;
    const int wave = tid >> 6;
    const int waveM = (wave >> 1) * 64;
    const int waveN = (wave & 1) * 64;
    const int mBase = blockIdx.x * 128;
    const int lr = tid >> 1;
    const int lh = (tid & 1) * 16;

    f32x4 acc[4][4];
#pragma unroll
    for (int i = 0; i < 4; ++i)
#pragma unroll
        for (int j = 0; j < 4; ++j) acc[i][j] = (f32x4){0.f, 0.f, 0.f, 0.f};

    const unsigned short* ap = S1 + (size_t)(mBase + lr) * K + lh;
    const unsigned short* bp1 = B1 + (size_t)lr * K + lh;
    const unsigned short* bp2 = B2 + (size_t)lr * K + lh;

    const int fr = lane & 15;
    const int fo = (lane >> 4) * 8;

#pragma unroll 2
    for (int k0 = 0; k0 < K; k0 += 32) {
        uint4 saa = *(const uint4*)(ap + k0), sab = *(const uint4*)(ap + k0 + 8);
        uint4 w1a = *(const uint4*)(bp1 + k0), w1b = *(const uint4*)(bp1 + k0 + 8);
        uint4 w2a = *(const uint4*)(bp2 + k0), w2b = *(const uint4*)(bp2 + k0 + 8);

        __syncthreads();
        {
            unsigned short* aw = &As[lr * LDSX + lh];
            *(uint4*)aw = saa; *(uint4*)(aw + 8) = sab;
            unsigned short* bw0 = &Bs[0][lr * LDSX + lh];
            *(uint4*)bw0 = w1a; *(uint4*)(bw0 + 8) = w1b;
            unsigned short* bw1 = &Bs[1][lr * LDSX + lh];
            *(uint4*)bw1 = w2a; *(uint4*)(bw1 + 8) = w2b;
        }
        __syncthreads();

        half8 av[4];
#pragma unroll
        for (int i = 0; i < 4; ++i)
            av[i] = *(const half8*)&As[(waveM + i * 16 + fr) * LDSX + fo];
#pragma unroll
        for (int j = 0; j < 4; ++j) {
            int ro = (waveN + j * 16 + fr) * LDSX + fo;
            half8 b1v = *(const half8*)&Bs[0][ro];
            half8 b2v = *(const half8*)&Bs[1][ro];
#pragma unroll
            for (int i = 0; i < 4; ++i) {
                acc[i][j] = MFMA_F16(av[i], b1v, acc[i][j]);
                acc[i][j] = MFMA_F16(av[i], b2v, acc[i][j]);
            }
        }
    }

    const int qr = (lane >> 4) * 4;
#pragma unroll
    for (int j = 0; j < 4; ++j) {
        float bv = bias[waveN + j * 16 + fr];
#pragma unroll
        for (int i = 0; i < 4; ++i) {
            float* cp = C + (size_t)(mBase + waveM + i * 16 + qr) * 128
                          + (waveN + j * 16 + fr);
#pragma unroll
            for (int r = 0; r < 4; ++r)
                cp[(size_t)r * 128] = acc[i][j][r] + bv;
        }
    }
}

// Layer-1 speculative chunked LIF scan. 256 threads = 256 channels.
// grid (T/256, B). Spikes out as fp16 1.0 (0x3C00).
__global__ __launch_bounds__(256) void scan1_kernel(
    const float* __restrict__ A, unsigned short* __restrict__ S)
{
    const int b = blockIdx.y;
    const int c = threadIdx.x;
    const int t0 = blockIdx.x * 256;
    const int ts = (t0 >= 128) ? t0 - 128 : 0;

    const float* __restrict__ base = A + (size_t)b * 2048 * 256 + c;
    unsigned short* __restrict__ sb = S + (size_t)b * 2048 * 256 + c;

    float v = 0.0f;
    for (int t = ts; t < t0; t += 16) {
        float a[16];
#pragma unroll
        for (int k = 0; k < 16; ++k) a[k] = base[(size_t)(t + k) * 256];
#pragma unroll
        for (int k = 0; k < 16; ++k) {
            float h = v + (a[k] - v) * 0.5f;
            v = (h >= 1.0f) ? 0.0f : h;
        }
    }
    for (int t = t0; t < t0 + 256; t += 16) {
        float a[16];
#pragma unroll
        for (int k = 0; k < 16; ++k) a[k] = base[(size_t)(t + k) * 256];
#pragma unroll
        for (int k = 0; k < 16; ++k) {
            float h = v + (a[k] - v) * 0.5f;
            bool sp = (h >= 1.0f);
            v = sp ? 0.0f : h;
            sb[(size_t)(t + k) * 256] = sp ? (unsigned short)0x3C00 : (unsigned short)0;
        }
    }
}

// Layer-2 scan fused with residual + LayerNorm. grid (T/256, B), 256 threads.
// Threads 0..127 scan channels; all 4 waves do row-wise LN on LDS-buffered y.
__global__ __launch_bounds__(256) void scan2_ln_kernel(
    const float* __restrict__ A2, const float* __restrict__ X,
    const float* __restrict__ lnw, const float* __restrict__ lnb,
    float* __restrict__ out)
{
    __shared__ float ybuf[128 * 132];
    const int tid = threadIdx.x;
    const int lane = tid & 63;
    const int wave = tid >> 6;
    const int b = blockIdx.y;
    const int t0 = blockIdx.x * 256;
    const int ts = (t0 >= 128) ? t0 - 128 : 0;

    const float* __restrict__ a2p = A2 + (size_t)b * 2048 * 128 + tid;
    const float* __restrict__ xp  = X  + (size_t)b * 2048 * 128 + tid;

    float2 wv = *(const float2*)(lnw + lane * 2);
    float2 bv = *(const float2*)(lnb + lane * 2);

    float v = 0.0f;
    if (tid < 128) {
        for (int t = ts; t < t0; t += 16) {
            float a[16];
#pragma unroll
            for (int k = 0; k < 16; ++k) a[k] = a2p[(size_t)(t + k) * 128];
#pragma unroll
            for (int k = 0; k < 16; ++k) {
                float h = v + (a[k] - v) * 0.5f;
                v = (h >= 1.0f) ? 0.0f : h;
            }
        }
    }

    for (int r = 0; r < 2; ++r) {
        const int tr = t0 + r * 128;
        if (tid < 128) {
            for (int tb = 0; tb < 128; tb += 16) {
                float a[16], xx[16];
#pragma unroll
                for (int k = 0; k < 16; ++k) a[k]  = a2p[(size_t)(tr + tb + k) * 128];
#pragma unroll
                for (int k = 0; k < 16; ++k) xx[k] = xp[(size_t)(tr + tb + k) * 128];
#pragma unroll
                for (int k = 0; k < 16; ++k) {
                    float h = v + (a[k] - v) * 0.5f;
                    bool sp = (h >= 1.0f);
                    v = sp ? 0.0f : h;
                    ybuf[(tb + k) * 132 + tid] = xx[k] + (sp ? 1.0f : 0.0f);
                }
            }
        }
        __syncthreads();
#pragma unroll 4
        for (int rr = 0; rr < 32; ++rr) {
            const int lrow = rr * 4 + wave;
            float2 y = *(const float2*)&ybuf[lrow * 132 + lane * 2];
            float sum = y.x + y.y;
            float ss = y.x * y.x + y.y * y.y;
#pragma unroll
            for (int off = 32; off > 0; off >>= 1) {
                sum += __shfl_xor(sum, off, 64);
                ss  += __shfl_xor(ss, off, 64);
            }
            float mu = sum * (1.0f / 128.0f);
            float var = ss * (1.0f / 128.0f) - mu * mu;
            float inv = rsqrtf(var + 1e-5f);
            float2 o;
            o.x = (y.x - mu) * inv * wv.x + bv.x;
            o.y = (y.y - mu) * inv * wv.y + bv.y;
            *(float2*)(out + (size_t)(b * 2048 + tr + lrow) * 128 + lane * 2) = o;
        }
        __syncthreads();
    }
}

extern "C" void kernel_launch(void* const* d_in, const int* in_sizes, int n_in,
                              void* d_out, int out_size, void* d_ws, size_t ws_size,
                              hipStream_t stream)
{
    const float* x   = (const float*)d_in[0];
    const float* W1  = (const float*)d_in[1];
    const float* b1  = (const float*)d_in[2];
    const float* W2  = (const float*)d_in[3];
    const float* b2  = (const float*)d_in[4];
    const float* lnw = (const float*)d_in[5];
    const float* lnb = (const float*)d_in[6];
    float* out = (float*)d_out;

    const int M = 65536, T = 2048;
    char* ws = (char*)d_ws;
    float* A = (float*)ws;                                   // h1 [M][256], then h2 [M][128]
    unsigned short* S1 = (unsigned short*)(ws + 67108864);   // [M][256] fp16
    unsigned short* Wp = (unsigned short*)(ws + 100663296);  // 4 planes x 32768

    wsplit_kernel<<<256, 256, 0, stream>>>(W1, W2, Wp);
    dim3 gG1(M / 128, 2);
    gemm1_kernel<<<gG1, 256, 0, stream>>>(x, Wp, Wp + 32768, b1, A);
    dim3 gScan(T / 256, 32);
    scan1_kernel<<<gScan, 256, 0, stream>>>(A, S1);
    dim3 gG2(M / 128, 1);
    gemm2_kernel<<<gG2, 256, 0, stream>>>(S1, Wp + 65536, Wp + 98304, b2, A);
    scan2_ln_kernel<<<gScan, 256, 0, stream>>>(A, x, lnw, lnb, out);
}